// Round 8
// baseline (24.236 us; speedup 1.0000x reference)
//
#include <hip/hip_runtime.h>

#define CC 8
#define HW 4096
#define L2E 1.4426950408889634f

typedef __attribute__((ext_vector_type(4))) float f32x4;

// ---------------- Node 1: Gram/rowsum partials only ----------------
// 256 blocks (4 batches x 64 chunks) x 64 threads (1 wave). Butterfly at
// 1 wave/CU so the DS-pipe cost (~264 instrs) fully parallelizes.
__global__ __launch_bounds__(64) void kGram(const float* __restrict__ x,
                                            float* __restrict__ ws)
{
  const int b = blockIdx.x >> 6, chunk = blockIdx.x & 63;
  const int ln = threadIdx.x;
  const int n = chunk * 64 + ln;
  const float* xb = x + b * CC * HW;

  float xv[CC];
  #pragma unroll
  for (int c = 0; c < CC; ++c) xv[c] = xb[c * HW + n];

  float acc[44];
  {
    int k = 0;
    #pragma unroll
    for (int c = 0; c < CC; ++c) {
      #pragma unroll
      for (int d = c; d < CC; ++d) { acc[k] = xv[c] * xv[d]; ++k; }
    }
    #pragma unroll
    for (int c = 0; c < CC; ++c) acc[36 + c] = xv[c];
  }
  #pragma unroll
  for (int i = 0; i < 44; ++i) {
    float v = acc[i];
    #pragma unroll
    for (int off = 32; off > 0; off >>= 1) v += __shfl_xor(v, off, 64);
    acc[i] = v;
  }
  if (ln == 0) {
    #pragma unroll
    for (int i = 0; i < 44; ++i) ws[blockIdx.x * 44 + i] = acc[i];  // static idx
  }
}

// ---------------- Node 2: kv build + PAM direct + CAM + epilogue ----------------
// 256 blocks (4 batches x 64-pixel tiles) x 512 threads (8 waves, ~1 block/CU).
__global__ __launch_bounds__(512) void kMain(
    const float* __restrict__ x,
    const float* __restrict__ cwq, const float* __restrict__ cbq,
    const float* __restrict__ cwk, const float* __restrict__ cbk,
    const float* __restrict__ cwv, const float* __restrict__ cbv,
    const float* __restrict__ pwq, const float* __restrict__ pbq,
    const float* __restrict__ pwk, const float* __restrict__ pbk,
    const float* __restrict__ pwv, const float* __restrict__ pbv,
    const float* __restrict__ ws, float* __restrict__ out)
{
  const int b = blockIdx.x >> 6, tile = blockIdx.x & 63;
  const int n0 = tile * 64;
  const int t = threadIdx.x, ln = t & 63;
  const int wid = __builtin_amdgcn_readfirstlane(t >> 6);   // wave 0..7

  __shared__ __align__(16) float kv[HW * 2];                // 32 KB {k2,v} pairs
  __shared__ float redd[8][64], redn[8][64];                // 4 KB
  __shared__ float gpart[8][44];
  __shared__ float sums[44], Gl[64], Ll[64], Al[64], Mp[64], cvs[8], outp[64];

  const float* xb = x + b * CC * HW;

  // ---- P0a: kv for my 8 m's (m = 8t..8t+7): 128 fma, 4 b128 LDS writes ----
  {
    const int m8 = t * 8;
    f32x4 xa[CC], xc[CC];
    #pragma unroll
    for (int c = 0; c < CC; ++c) {
      xa[c] = *(const f32x4*)(xb + c * HW + m8);
      xc[c] = *(const f32x4*)(xb + c * HW + m8 + 4);
    }
    f32x4 o0, o1, o2, o3;
    #pragma unroll
    for (int j = 0; j < 8; ++j) {
      float kk = pbk[0], vv = pbv[0];
      #pragma unroll
      for (int c = 0; c < CC; ++c) {
        const float xv = (j < 4) ? xa[c][j & 3] : xc[c][j & 3];
        kk = fmaf(pwk[c], xv, kk);
        vv = fmaf(pwv[c], xv, vv);
      }
      kk *= L2E;
      if (j == 0) { o0[0] = kk; o0[1] = vv; }
      else if (j == 1) { o0[2] = kk; o0[3] = vv; }
      else if (j == 2) { o1[0] = kk; o1[1] = vv; }
      else if (j == 3) { o1[2] = kk; o1[3] = vv; }
      else if (j == 4) { o2[0] = kk; o2[1] = vv; }
      else if (j == 5) { o2[2] = kk; o2[3] = vv; }
      else if (j == 6) { o3[0] = kk; o3[1] = vv; }
      else             { o3[2] = kk; o3[3] = vv; }
    }
    f32x4* kv4 = (f32x4*)kv;
    kv4[t * 4 + 0] = o0; kv4[t * 4 + 1] = o1;
    kv4[t * 4 + 2] = o2; kv4[t * 4 + 3] = o3;
  }

  // ---- P0b: pq + xn for pixel n0+ln (redundant across waves, needed anyway) ----
  float xn[CC];
  #pragma unroll
  for (int c = 0; c < CC; ++c) xn[c] = xb[c * HW + n0 + ln];
  float a = pbq[0];
  #pragma unroll
  for (int c = 0; c < CC; ++c) a = fmaf(pwq[c], xn[c], a);

  // ---- P1: Gram partial rows: wave w sums rows b*64+w*8 .. +7 ----
  if (ln < 44) {
    const float* g = ws + (b * 64 + wid * 8) * 44 + ln;
    float s = 0.f;
    #pragma unroll
    for (int r = 0; r < 8; ++r) s += g[r * 44];
    gpart[wid][ln] = s;
  }
  __syncthreads();

  // ---- P2: PAM direct; wave wid covers m in [wid*512, wid*512+512) ----
  {
    const f32x4* kvw = ((const f32x4*)kv) + (wid << 8);     // 256 f32x4 = 512 m
    float dA = 0, dB = 0, dC = 0, dD = 0;
    float nA = 0, nB = 0, nC = 0, nD = 0;
    #pragma unroll 2
    for (int i = 0; i < 256; i += 4) {
      const f32x4 p0 = kvw[i], p1 = kvw[i + 1], p2 = kvw[i + 2], p3 = kvw[i + 3];
      float e;
      e = __builtin_amdgcn_exp2f(a * p0[0]); dA += e; nA = fmaf(e, p0[1], nA);
      e = __builtin_amdgcn_exp2f(a * p0[2]); dA += e; nA = fmaf(e, p0[3], nA);
      e = __builtin_amdgcn_exp2f(a * p1[0]); dB += e; nB = fmaf(e, p1[1], nB);
      e = __builtin_amdgcn_exp2f(a * p1[2]); dB += e; nB = fmaf(e, p1[3], nB);
      e = __builtin_amdgcn_exp2f(a * p2[0]); dC += e; nC = fmaf(e, p2[1], nC);
      e = __builtin_amdgcn_exp2f(a * p2[2]); dC += e; nC = fmaf(e, p2[3], nC);
      e = __builtin_amdgcn_exp2f(a * p3[0]); dD += e; nD = fmaf(e, p3[1], nD);
      e = __builtin_amdgcn_exp2f(a * p3[2]); dD += e; nD = fmaf(e, p3[3], nD);
    }
    redd[wid][ln] = (dA + dB) + (dC + dD);
    redn[wid][ln] = (nA + nB) + (nC + nD);
  }
  __syncthreads();

  // ---- P3: wave 0: PAM combine + Gram total ----
  if (t < 64) {
    float D = 0.f, N = 0.f;
    #pragma unroll
    for (int s = 0; s < 8; ++s) { D += redd[s][t]; N += redn[s][t]; }
    outp[t] = N / D;
  }
  if (t < 44) {
    float s = 0.f;
    #pragma unroll
    for (int w = 0; w < 8; ++w) s += gpart[w][t];
    sums[t] = s;
  }
  __syncthreads();

  const int c = ln >> 3, d = ln & 7;
  if (t < 64) {
    const int lo = min(c, d), hi = max(c, d);
    Gl[t] = sums[lo * 8 + hi - lo * (lo + 1) / 2];
  }
  __syncthreads();

  float Lv = 0.f;
  if (t < 64) {
    float qs = 0.f, ks = 0.f;
    #pragma unroll
    for (int e = 0; e < 8; ++e) {
      qs = fmaf(cwq[c * 8 + e], sums[36 + e], qs);
      ks = fmaf(cwk[d * 8 + e], sums[36 + e], ks);
    }
    float A = 0.f;
    #pragma unroll
    for (int e = 0; e < 8; ++e) {
      float inner = 0.f;
      #pragma unroll
      for (int f = 0; f < 8; ++f) inner = fmaf(Gl[e * 8 + f], cwk[d * 8 + f], inner);
      A = fmaf(cwq[c * 8 + e], inner, A);
    }
    Lv = A + qs * cbk[d] + cbq[c] * ks + 4096.f * cbq[c] * cbk[d];
    Ll[t] = Lv;
  }
  __syncthreads();

  if (t < 64) {
    float mx = -INFINITY;
    #pragma unroll
    for (int f = 0; f < 8; ++f) mx = fmaxf(mx, Ll[c * 8 + f]);
    float ssum = 0.f;
    #pragma unroll
    for (int f = 0; f < 8; ++f) ssum += __expf(Ll[c * 8 + f] - mx);
    Al[t] = __expf(Lv - mx) / ssum;
  }
  __syncthreads();

  if (t < 64) {
    float M = 0.f;
    #pragma unroll
    for (int f = 0; f < 8; ++f) M = fmaf(Al[c * 8 + f], cwv[f * 8 + d], M);
    if (d == c) M += 2.f;            // +2I: residual x appears in both CAM and PAM
    Mp[t] = M;
    if (d == 0) {
      float cvv = 0.f;
      #pragma unroll
      for (int f = 0; f < 8; ++f) cvv = fmaf(Al[c * 8 + f], cbv[f], cvv);
      cvs[c] = cvv;
    }
  }
  __syncthreads();

  // ---- P5: epilogue, thread (wid, ln) -> channel wid, pixel n0+ln ----
  {
    float o = cvs[wid] + outp[ln];
    #pragma unroll
    for (int dd = 0; dd < 8; ++dd) o = fmaf(Mp[wid * 8 + dd], xn[dd], o);
    out[(b * 8 + wid) * HW + n0 + ln] = o;
  }
}

extern "C" void kernel_launch(void* const* d_in, const int* in_sizes, int n_in,
                              void* d_out, int out_size, void* d_ws, size_t ws_size,
                              hipStream_t stream) {
  const float* x   = (const float*)d_in[0];
  const float* cwq = (const float*)d_in[1];
  const float* cbq = (const float*)d_in[2];
  const float* cwk = (const float*)d_in[3];
  const float* cbk = (const float*)d_in[4];
  const float* cwv = (const float*)d_in[5];
  const float* cbv = (const float*)d_in[6];
  const float* pwq = (const float*)d_in[7];
  const float* pbq = (const float*)d_in[8];
  const float* pwk = (const float*)d_in[9];
  const float* pbk = (const float*)d_in[10];
  const float* pwv = (const float*)d_in[11];
  const float* pbv = (const float*)d_in[12];
  float* ws  = (float*)d_ws;
  float* out = (float*)d_out;

  hipLaunchKernelGGL(kGram, dim3(256), dim3(64), 0, stream, x, ws);
  hipLaunchKernelGGL(kMain, dim3(256), dim3(512), 0, stream,
                     x, cwq, cbq, cwk, cbk, cwv, cbv,
                     pwq, pbq, pwk, pbk, pwv, pbv, ws, out);
}

// Round 9
// 21.631 us; speedup vs baseline: 1.1204x; 1.1204x over previous
//
#include <hip/hip_runtime.h>

#define CC 8
#define HW 4096
#define L2E 1.4426950408889634f

typedef __attribute__((ext_vector_type(4))) float f32x4;

// Full-wave (64-lane) sum reduction on the VALU pipe via DPP.
// Canonical gfx9 sequence; total lands in lane 63. No DS-pipe traffic
// (R6's lesson: 8+ waves of ds_swizzle butterflies serialize on the DS pipe).
static __device__ __forceinline__ float dpp_sum64(float v) {
#define DPPSTEP(CTRL, RM, BM)                                              \
  v += __int_as_float(__builtin_amdgcn_update_dpp(                         \
      0, __float_as_int(v), CTRL, RM, BM, true));
  DPPSTEP(0x111, 0xf, 0xf)   // row_shr:1
  DPPSTEP(0x112, 0xf, 0xf)   // row_shr:2
  DPPSTEP(0x114, 0xf, 0xe)   // row_shr:4
  DPPSTEP(0x118, 0xf, 0xc)   // row_shr:8  -> lane15/31/47/63 = row sums
  DPPSTEP(0x142, 0xa, 0xf)   // row_bcast:15 -> lane31 = r0+r1, lane63 = r2+r3
  DPPSTEP(0x143, 0xc, 0xf)   // row_bcast:31 -> lane63 = total
#undef DPPSTEP
  return v;
}

// Single node: 256 blocks (4 batches x 64-pixel tiles) x 512 threads (8 waves).
//   P0a: kv build for 8 m's/thread (covers all 4096 m) -> 32 KB LDS
//   P0b: Gram/rowsum partials from the SAME registers, DPP-reduced per wave
//   P0c: pq + xn for this lane's pixel
//   P2 : PAM rank-1 softmax, wave w scans m in [w*512, w*512+512)
//   P3 : wave 0 combines PAM partials + CAM 8x8 softmax
//   P4 : epilogue, thread (w, ln) -> channel w, pixel n0+ln
__global__ __launch_bounds__(512) void kFused(
    const float* __restrict__ x,
    const float* __restrict__ cwq, const float* __restrict__ cbq,
    const float* __restrict__ cwk, const float* __restrict__ cbk,
    const float* __restrict__ cwv, const float* __restrict__ cbv,
    const float* __restrict__ pwq, const float* __restrict__ pbq,
    const float* __restrict__ pwk, const float* __restrict__ pbk,
    const float* __restrict__ pwv, const float* __restrict__ pbv,
    float* __restrict__ out)
{
  const int b = blockIdx.x >> 6, tile = blockIdx.x & 63;
  const int n0 = tile * 64;
  const int t = threadIdx.x, ln = t & 63;
  const int wid = __builtin_amdgcn_readfirstlane(t >> 6);   // wave 0..7

  __shared__ __align__(16) float kv[HW * 2];                // 32 KB {k2,v} pairs
  __shared__ float redd[8][64], redn[8][64];                // 4 KB
  __shared__ float gpart[8][44];
  __shared__ float sums[44], Gl[64], Ll[64], Al[64], Mp[64], cvs[8], outp[64];

  const float* xb = x + b * CC * HW;

  // ---- P0a: kv for my 8 m's (m = 8t..8t+7); keep x regs for Gram ----
  f32x4 xa[CC], xc[CC];
  {
    const int m8 = t * 8;
    #pragma unroll
    for (int c = 0; c < CC; ++c) {
      xa[c] = *(const f32x4*)(xb + c * HW + m8);
      xc[c] = *(const f32x4*)(xb + c * HW + m8 + 4);
    }
    f32x4 o0, o1, o2, o3;
    #pragma unroll
    for (int j = 0; j < 8; ++j) {
      float kk = pbk[0], vv = pbv[0];
      #pragma unroll
      for (int c = 0; c < CC; ++c) {
        const float xv = (j < 4) ? xa[c][j & 3] : xc[c][j & 3];
        kk = fmaf(pwk[c], xv, kk);
        vv = fmaf(pwv[c], xv, vv);
      }
      kk *= L2E;
      if (j == 0) { o0[0] = kk; o0[1] = vv; }
      else if (j == 1) { o0[2] = kk; o0[3] = vv; }
      else if (j == 2) { o1[0] = kk; o1[1] = vv; }
      else if (j == 3) { o1[2] = kk; o1[3] = vv; }
      else if (j == 4) { o2[0] = kk; o2[1] = vv; }
      else if (j == 5) { o2[2] = kk; o2[3] = vv; }
      else if (j == 6) { o3[0] = kk; o3[1] = vv; }
      else             { o3[2] = kk; o3[3] = vv; }
    }
    f32x4* kv4 = (f32x4*)kv;
    kv4[t * 4 + 0] = o0; kv4[t * 4 + 1] = o1;
    kv4[t * 4 + 2] = o2; kv4[t * 4 + 3] = o3;
  }

  // ---- P0b: Gram + rowsum partials from the already-loaded registers ----
  {
    float acc[44];
    #pragma unroll
    for (int i = 0; i < 44; ++i) acc[i] = 0.f;
    #pragma unroll
    for (int j = 0; j < 8; ++j) {
      float xv[CC];
      #pragma unroll
      for (int c = 0; c < CC; ++c) xv[c] = (j < 4) ? xa[c][j & 3] : xc[c][j & 3];
      int k = 0;
      #pragma unroll
      for (int c = 0; c < CC; ++c) {
        #pragma unroll
        for (int d = c; d < CC; ++d) { acc[k] = fmaf(xv[c], xv[d], acc[k]); ++k; }
      }
      #pragma unroll
      for (int c = 0; c < CC; ++c) acc[36 + c] += xv[c];
    }
    #pragma unroll
    for (int i = 0; i < 44; ++i) acc[i] = dpp_sum64(acc[i]);
    if (ln == 63) {
      #pragma unroll
      for (int i = 0; i < 44; ++i) gpart[wid][i] = acc[i];   // static idx
    }
  }

  // ---- P0c: pq + xn for pixel n0+ln ----
  float xn[CC];
  #pragma unroll
  for (int c = 0; c < CC; ++c) xn[c] = xb[c * HW + n0 + ln];
  float a = pbq[0];
  #pragma unroll
  for (int c = 0; c < CC; ++c) a = fmaf(pwq[c], xn[c], a);

  __syncthreads();

  // ---- P2: PAM direct; wave wid covers m in [wid*512, wid*512+512) ----
  {
    const f32x4* kvw = ((const f32x4*)kv) + (wid << 8);     // 256 f32x4 = 512 m
    float dA = 0, dB = 0, dC = 0, dD = 0;
    float nA = 0, nB = 0, nC = 0, nD = 0;
    #pragma unroll 2
    for (int i = 0; i < 256; i += 4) {
      const f32x4 p0 = kvw[i], p1 = kvw[i + 1], p2 = kvw[i + 2], p3 = kvw[i + 3];
      float e;
      e = __builtin_amdgcn_exp2f(a * p0[0]); dA += e; nA = fmaf(e, p0[1], nA);
      e = __builtin_amdgcn_exp2f(a * p0[2]); dA += e; nA = fmaf(e, p0[3], nA);
      e = __builtin_amdgcn_exp2f(a * p1[0]); dB += e; nB = fmaf(e, p1[1], nB);
      e = __builtin_amdgcn_exp2f(a * p1[2]); dB += e; nB = fmaf(e, p1[3], nB);
      e = __builtin_amdgcn_exp2f(a * p2[0]); dC += e; nC = fmaf(e, p2[1], nC);
      e = __builtin_amdgcn_exp2f(a * p2[2]); dC += e; nC = fmaf(e, p2[3], nC);
      e = __builtin_amdgcn_exp2f(a * p3[0]); dD += e; nD = fmaf(e, p3[1], nD);
      e = __builtin_amdgcn_exp2f(a * p3[2]); dD += e; nD = fmaf(e, p3[3], nD);
    }
    redd[wid][ln] = (dA + dB) + (dC + dD);
    redn[wid][ln] = (nA + nB) + (nC + nD);
  }
  __syncthreads();

  // ---- P3: wave 0: PAM combine + Gram total + CAM 8x8 softmax ----
  if (t < 64) {
    float D = 0.f, N = 0.f;
    #pragma unroll
    for (int s = 0; s < 8; ++s) { D += redd[s][t]; N += redn[s][t]; }
    outp[t] = N / D;
  }
  if (t < 44) {
    float s = 0.f;
    #pragma unroll
    for (int w = 0; w < 8; ++w) s += gpart[w][t];
    sums[t] = s;
  }
  __syncthreads();

  const int c = ln >> 3, d = ln & 7;
  if (t < 64) {
    const int lo = min(c, d), hi = max(c, d);
    Gl[t] = sums[lo * 8 + hi - lo * (lo + 1) / 2];
  }
  __syncthreads();

  float Lv = 0.f;
  if (t < 64) {
    float qs = 0.f, ks = 0.f;
    #pragma unroll
    for (int e = 0; e < 8; ++e) {
      qs = fmaf(cwq[c * 8 + e], sums[36 + e], qs);
      ks = fmaf(cwk[d * 8 + e], sums[36 + e], ks);
    }
    float A = 0.f;
    #pragma unroll
    for (int e = 0; e < 8; ++e) {
      float inner = 0.f;
      #pragma unroll
      for (int f = 0; f < 8; ++f) inner = fmaf(Gl[e * 8 + f], cwk[d * 8 + f], inner);
      A = fmaf(cwq[c * 8 + e], inner, A);
    }
    Lv = A + qs * cbk[d] + cbq[c] * ks + 4096.f * cbq[c] * cbk[d];
    Ll[t] = Lv;
  }
  __syncthreads();

  if (t < 64) {
    float mx = -INFINITY;
    #pragma unroll
    for (int f = 0; f < 8; ++f) mx = fmaxf(mx, Ll[c * 8 + f]);
    float ssum = 0.f;
    #pragma unroll
    for (int f = 0; f < 8; ++f) ssum += __expf(Ll[c * 8 + f] - mx);
    Al[t] = __expf(Lv - mx) / ssum;
  }
  __syncthreads();

  if (t < 64) {
    float M = 0.f;
    #pragma unroll
    for (int f = 0; f < 8; ++f) M = fmaf(Al[c * 8 + f], cwv[f * 8 + d], M);
    if (d == c) M += 2.f;            // +2I: residual x appears in both CAM and PAM
    Mp[t] = M;
    if (d == 0) {
      float cvv = 0.f;
      #pragma unroll
      for (int f = 0; f < 8; ++f) cvv = fmaf(Al[c * 8 + f], cbv[f], cvv);
      cvs[c] = cvv;
    }
  }
  __syncthreads();

  // ---- P4: epilogue, thread (wid, ln) -> channel wid, pixel n0+ln ----
  {
    float o = cvs[wid] + outp[ln];
    #pragma unroll
    for (int dd = 0; dd < 8; ++dd) o = fmaf(Mp[wid * 8 + dd], xn[dd], o);
    out[(b * 8 + wid) * HW + n0 + ln] = o;
  }
}

extern "C" void kernel_launch(void* const* d_in, const int* in_sizes, int n_in,
                              void* d_out, int out_size, void* d_ws, size_t ws_size,
                              hipStream_t stream) {
  const float* x   = (const float*)d_in[0];
  const float* cwq = (const float*)d_in[1];
  const float* cbq = (const float*)d_in[2];
  const float* cwk = (const float*)d_in[3];
  const float* cbk = (const float*)d_in[4];
  const float* cwv = (const float*)d_in[5];
  const float* cbv = (const float*)d_in[6];
  const float* pwq = (const float*)d_in[7];
  const float* pbq = (const float*)d_in[8];
  const float* pwk = (const float*)d_in[9];
  const float* pbk = (const float*)d_in[10];
  const float* pwv = (const float*)d_in[11];
  const float* pbv = (const float*)d_in[12];
  float* out = (float*)d_out;

  hipLaunchKernelGGL(kFused, dim3(256), dim3(512), 0, stream,
                     x, cwq, cbq, cwk, cbk, cwv, cbv,
                     pwq, pbq, pwk, pbk, pwv, pbv, out);
}